// Round 1
// baseline (362.709 us; speedup 1.0000x reference)
//
#include <hip/hip_runtime.h>
#include <hip/hip_bf16.h>

#define N_NODES 20000
#define N_EDGES 320000
#define IN_DIM  256
#define HALF    128
#define OUT_DIM 256
#define BN_EPS  1e-5f

// ---------------------------------------------------------------------------
// CSR build: count, exclusive-scan, fill
// ---------------------------------------------------------------------------
__global__ void count_kernel(const int* __restrict__ src, const int* __restrict__ dst,
                             int* __restrict__ cntF, int* __restrict__ cntB) {
    int e = blockIdx.x * blockDim.x + threadIdx.x;
    if (e < N_EDGES) {
        atomicAdd(&cntF[dst[e]], 1);   // fwd: aggregate at dst
        atomicAdd(&cntB[src[e]], 1);   // bwd: aggregate at src
    }
}

__global__ __launch_bounds__(1024) void scan_kernel(const int* __restrict__ cntF, int* __restrict__ offF,
                                                    const int* __restrict__ cntB, int* __restrict__ offB) {
    const int* in  = blockIdx.x ? cntB : cntF;
    int*       out = blockIdx.x ? offB : offF;
    __shared__ int sh[1024];
    int tid = threadIdx.x;
    int carry = 0;
    for (int base = 0; base < N_NODES; base += 1024) {
        int i = base + tid;
        int v = (i < N_NODES) ? in[i] : 0;
        sh[tid] = v;
        __syncthreads();
        // Hillis-Steele inclusive scan
        for (int o = 1; o < 1024; o <<= 1) {
            int t = (tid >= o) ? sh[tid - o] : 0;
            __syncthreads();
            sh[tid] += t;
            __syncthreads();
        }
        if (i < N_NODES) out[i] = carry + sh[tid] - v;  // exclusive
        carry += sh[1023];
        __syncthreads();
    }
    if (tid == 0) out[N_NODES] = carry;
}

__global__ void fill_kernel(const int* __restrict__ src, const int* __restrict__ dst,
                            const int* __restrict__ offF, const int* __restrict__ offB,
                            int* __restrict__ curF, int* __restrict__ curB,
                            int* __restrict__ listF, int* __restrict__ listB) {
    int e = blockIdx.x * blockDim.x + threadIdx.x;
    if (e < N_EDGES) {
        int s = src[e], d = dst[e];
        int p = atomicAdd(&curF[d], 1);
        listF[offF[d] + p] = s;
        int q = atomicAdd(&curB[s], 1);
        listB[offB[s] + q] = d;
    }
}

// ---------------------------------------------------------------------------
// Fused GEMM: Ylogical = x @ [W_l_f; W_l_b; W_r_f; W_r_b].T   (M=20000, N=512, K=256)
//   cols [0,256)  -> Y (bf16) : projected features for aggregation
//   cols [256,512)-> Z (fp32) : residual term, written straight into d_out
// fp32 tiled 64x64, K-step 16, 4x4 per thread.
// ---------------------------------------------------------------------------
#define TM 64
#define TN 64
#define TK 16

__global__ __launch_bounds__(256) void gemm_kernel(
    const float* __restrict__ x,
    const float* __restrict__ Wlf, const float* __restrict__ Wrf,
    const float* __restrict__ Wlb, const float* __restrict__ Wrb,
    __hip_bfloat16* __restrict__ Y, float* __restrict__ Z)
{
    __shared__ float As[TK][TM + 4];
    __shared__ float Bs[TK][TN + 4];
    int mBase = blockIdx.x * TM;
    int nBase = blockIdx.y * TN;           // logical n in [0,512)
    int tid = threadIdx.x;
    int tx = tid & 15, ty = tid >> 4;
    int m0 = ty * 4, n0 = tx * 4;
    float acc[4][4] = {};

    for (int k0 = 0; k0 < IN_DIM; k0 += TK) {
        {   // A tile: 64 rows x 16 k
            int row = tid >> 2, kq = tid & 3;
            int gm = mBase + row;
            float4 v = make_float4(0.f, 0.f, 0.f, 0.f);
            if (gm < N_NODES) v = *(const float4*)(x + (size_t)gm * IN_DIM + k0 + kq * 4);
            As[kq * 4 + 0][row] = v.x; As[kq * 4 + 1][row] = v.y;
            As[kq * 4 + 2][row] = v.z; As[kq * 4 + 3][row] = v.w;
        }
        {   // B tile: 64 logical cols x 16 k  (B[k][n] = Wrow(n)[k])
            int col = tid >> 2, kq = tid & 3;
            int n = nBase + col;
            const float* Wrow;
            if      (n < 128) Wrow = Wlf + (size_t)n * IN_DIM;
            else if (n < 256) Wrow = Wlb + (size_t)(n - 128) * IN_DIM;
            else if (n < 384) Wrow = Wrf + (size_t)(n - 256) * IN_DIM;
            else              Wrow = Wrb + (size_t)(n - 384) * IN_DIM;
            float4 v = *(const float4*)(Wrow + k0 + kq * 4);
            Bs[kq * 4 + 0][col] = v.x; Bs[kq * 4 + 1][col] = v.y;
            Bs[kq * 4 + 2][col] = v.z; Bs[kq * 4 + 3][col] = v.w;
        }
        __syncthreads();
        #pragma unroll
        for (int kk = 0; kk < TK; ++kk) {
            float a[4], b[4];
            *(float4*)a = *(const float4*)&As[kk][m0];
            *(float4*)b = *(const float4*)&Bs[kk][n0];
            #pragma unroll
            for (int i = 0; i < 4; ++i)
                #pragma unroll
                for (int j = 0; j < 4; ++j)
                    acc[i][j] = fmaf(a[i], b[j], acc[i][j]);
        }
        __syncthreads();
    }

    #pragma unroll
    for (int i = 0; i < 4; ++i) {
        int gm = mBase + m0 + i;
        if (gm >= N_NODES) break;
        #pragma unroll
        for (int j = 0; j < 4; ++j) {
            int n = nBase + n0 + j;
            if (n < 256) Y[(size_t)gm * 256 + n] = __float2bfloat16(acc[i][j]);
            else         Z[(size_t)gm * 256 + (n - 256)] = acc[i][j];
        }
    }
}

// ---------------------------------------------------------------------------
// Aggregation + bias + residual, with BN-stat partial accumulation.
// Block = 256 threads: tid<128 -> fwd col tid, tid>=128 -> bwd col tid-128.
// Each block handles 16 nodes; per-thread register partials -> 2 atomics.
// Output column layout == concat([h_fwd, h_bwd]) == tid.
// ---------------------------------------------------------------------------
#define AGG_NB 16
__global__ __launch_bounds__(256) void aggregate_kernel(
    const __hip_bfloat16* __restrict__ Y,
    const int* __restrict__ offF, const int* __restrict__ listF,
    const int* __restrict__ offB, const int* __restrict__ listB,
    const float* __restrict__ blf, const float* __restrict__ blb,
    float* __restrict__ H, float* __restrict__ stats)
{
    int tid = threadIdx.x;
    int nodeBase = blockIdx.x * AGG_NB;
    bool bwd = tid >= 128;
    int c = tid & 127;
    const int* off  = bwd ? offB  : offF;
    const int* list = bwd ? listB : listF;
    float bias = bwd ? blb[c] : blf[c];
    int ycol = bwd ? (128 + c) : c;

    float s1 = 0.f, s2 = 0.f;
    for (int j = 0; j < AGG_NB; ++j) {
        int n = nodeBase + j;
        if (n >= N_NODES) break;
        int beg = off[n], end = off[n + 1];
        float acc = 0.f;
        for (int i = beg; i < end; ++i) {
            int u = list[i];
            acc += __bfloat162float(Y[(size_t)u * 256 + ycol]);
        }
        float deg = (float)(end - beg);
        float h = acc / fmaxf(deg, 1.f) + bias + H[(size_t)n * 256 + tid];
        H[(size_t)n * 256 + tid] = h;
        s1 += h;
        s2 += h * h;
    }
    atomicAdd(&stats[tid], s1);
    atomicAdd(&stats[256 + tid], s2);
}

// ---------------------------------------------------------------------------
// BatchNorm finalize + ReLU, in place on d_out.
// ---------------------------------------------------------------------------
__global__ __launch_bounds__(256) void bn_kernel(
    const float* __restrict__ stats, const float* __restrict__ gamma,
    const float* __restrict__ beta, float* __restrict__ H)
{
    __shared__ float sc[256], sf[256];
    int tid = threadIdx.x;
    {
        float mean = stats[tid] * (1.f / N_NODES);
        float var  = stats[256 + tid] * (1.f / N_NODES) - mean * mean;
        float s = rsqrtf(var + BN_EPS) * gamma[tid];
        sc[tid] = s;
        sf[tid] = beta[tid] - mean * s;
    }
    __syncthreads();
    for (int n = blockIdx.x; n < N_NODES; n += gridDim.x) {
        size_t idx = (size_t)n * 256 + tid;
        float h = H[idx];
        H[idx] = fmaxf(h * sc[tid] + sf[tid], 0.f);
    }
}

// ---------------------------------------------------------------------------
extern "C" void kernel_launch(void* const* d_in, const int* in_sizes, int n_in,
                              void* d_out, int out_size, void* d_ws, size_t ws_size,
                              hipStream_t stream) {
    const float* x     = (const float*)d_in[0];
    const int*   edge  = (const int*)d_in[1];   // [2][N_EDGES]
    const float* Wlf   = (const float*)d_in[2];
    const float* blf   = (const float*)d_in[3];
    const float* Wrf   = (const float*)d_in[4];
    const float* Wlb   = (const float*)d_in[5];
    const float* blb   = (const float*)d_in[6];
    const float* Wrb   = (const float*)d_in[7];
    const float* gamma = (const float*)d_in[8];
    const float* beta  = (const float*)d_in[9];
    float* out = (float*)d_out;

    const int* src = edge;            // row 0
    const int* dst = edge + N_EDGES;  // row 1

    // workspace carve (256B-aligned chunks)
    char* ws = (char*)d_ws;
    size_t off = 0;
    auto alloc = [&](size_t bytes) { size_t r = off; off += (bytes + 255) & ~(size_t)255; return r; };
    __hip_bfloat16* Y = (__hip_bfloat16*)(ws + alloc((size_t)N_NODES * 256 * 2)); // 10.24 MB
    int* offF  = (int*)(ws + alloc((size_t)(N_NODES + 1) * 4));
    int* offB  = (int*)(ws + alloc((size_t)(N_NODES + 1) * 4));
    int* listF = (int*)(ws + alloc((size_t)N_EDGES * 4));
    int* listB = (int*)(ws + alloc((size_t)N_EDGES * 4));
    size_t zbase_off = off;
    int* cntF = (int*)(ws + alloc((size_t)N_NODES * 4));
    int* cntB = (int*)(ws + alloc((size_t)N_NODES * 4));
    int* curF = (int*)(ws + alloc((size_t)N_NODES * 4));
    int* curB = (int*)(ws + alloc((size_t)N_NODES * 4));
    float* stats = (float*)(ws + alloc(512 * 4));
    size_t zbytes = off - zbase_off;

    hipMemsetAsync(ws + zbase_off, 0, zbytes, stream);

    count_kernel<<<(N_EDGES + 255) / 256, 256, 0, stream>>>(src, dst, cntF, cntB);
    scan_kernel<<<2, 1024, 0, stream>>>(cntF, offF, cntB, offB);
    fill_kernel<<<(N_EDGES + 255) / 256, 256, 0, stream>>>(src, dst, offF, offB, curF, curB, listF, listB);

    dim3 ggrid((N_NODES + TM - 1) / TM, 512 / TN);
    gemm_kernel<<<ggrid, 256, 0, stream>>>(x, Wlf, Wrf, Wlb, Wrb, Y, out);

    aggregate_kernel<<<(N_NODES + AGG_NB - 1) / AGG_NB, 256, 0, stream>>>(
        Y, offF, listF, offB, listB, blf, blb, out, stats);

    bn_kernel<<<2048, 256, 0, stream>>>(stats, gamma, beta, out);
}

// Round 2
// 269.566 us; speedup vs baseline: 1.3455x; 1.3455x over previous
//
#include <hip/hip_runtime.h>
#include <hip/hip_bf16.h>

#define N_NODES 20000
#define N_EDGES 320000
#define BN_EPS  1e-5f

typedef __attribute__((ext_vector_type(4))) float f32x4;
typedef __attribute__((ext_vector_type(8))) float f32x8;
typedef __attribute__((ext_vector_type(8))) __bf16 bf16x8;

__device__ __forceinline__ unsigned short f2bf(float f) {   // RNE f32->bf16
    unsigned int u = __float_as_uint(f);
    u += 0x7fffu + ((u >> 16) & 1u);
    return (unsigned short)(u >> 16);
}

__device__ __forceinline__ void gload_lds16(const void* g, void* l) {
    __builtin_amdgcn_global_load_lds(
        (const __attribute__((address_space(1))) void*)g,
        (__attribute__((address_space(3))) void*)l, 16, 0, 0);
}

// ---------------------------------------------------------------------------
// CSR build: count, scan, fill
// ---------------------------------------------------------------------------
__global__ void count_kernel(const int* __restrict__ src, const int* __restrict__ dst,
                             int* __restrict__ cntF, int* __restrict__ cntB) {
    int e = blockIdx.x * blockDim.x + threadIdx.x;
    if (e < N_EDGES) {
        atomicAdd(&cntF[dst[e]], 1);
        atomicAdd(&cntB[src[e]], 1);
    }
}

#define SCAN_PER 20
__global__ __launch_bounds__(1024) void scan_kernel(const int* __restrict__ cntF, int* __restrict__ offF,
                                                    const int* __restrict__ cntB, int* __restrict__ offB) {
    const int* in  = blockIdx.x ? cntB : cntF;
    int*       out = blockIdx.x ? offB : offF;
    int t = threadIdx.x;
    int base = t * SCAN_PER;
    int v[SCAN_PER];
    int sum = 0;
    #pragma unroll
    for (int k = 0; k < SCAN_PER; ++k) {
        int i = base + k;
        int c = (i < N_NODES) ? in[i] : 0;
        v[k] = sum; sum += c;
    }
    __shared__ int sh[1024];
    sh[t] = sum;
    __syncthreads();
    for (int o = 1; o < 1024; o <<= 1) {
        int x = (t >= o) ? sh[t - o] : 0;
        __syncthreads();
        sh[t] += x;
        __syncthreads();
    }
    int pre = t ? sh[t - 1] : 0;
    #pragma unroll
    for (int k = 0; k < SCAN_PER; ++k) {
        int i = base + k;
        if (i < N_NODES) out[i] = pre + v[k];
    }
    if (t == 1023) out[N_NODES] = sh[1023];
}

__global__ void fill_kernel(const int* __restrict__ src, const int* __restrict__ dst,
                            const int* __restrict__ offF, const int* __restrict__ offB,
                            int* __restrict__ curF, int* __restrict__ curB,
                            int* __restrict__ listF, int* __restrict__ listB) {
    int e = blockIdx.x * blockDim.x + threadIdx.x;
    if (e < N_EDGES) {
        int s = src[e], d = dst[e];
        int p = atomicAdd(&curF[d], 1);
        listF[offF[d] + p] = s;
        int q = atomicAdd(&curB[s], 1);
        listB[offB[s] + q] = d;
    }
}

// ---------------------------------------------------------------------------
// MFMA GEMM: [20000,256] x [256 -> 512 outputs]; bf16 16x16x32 MFMA.
// grid.y: 0 -> Y cols 0:128 (W_l_f), 1 -> Y cols 128:256 (W_l_b),
//         2 -> Z cols 0:128 (W_r_f), 3 -> Z cols 128:256 (W_r_b)
// A/B staged fp32 via global_load_lds(16B) with XOR-quarter swizzle
// (pre-swizzled source + swizzled ds_read; stride 128B would be 16-way conflict).
// ---------------------------------------------------------------------------
__global__ __launch_bounds__(256) void mfma_gemm_kernel(
    const float* __restrict__ x,
    const float* __restrict__ Wlf, const float* __restrict__ Wlb,
    const float* __restrict__ Wrf, const float* __restrict__ Wrb,
    unsigned short* __restrict__ Y, float* __restrict__ Z)
{
    __shared__ float As[128 * 32];
    __shared__ float Bs[128 * 32];
    int by = blockIdx.y;
    int mBase = blockIdx.x * 128;
    int tid = threadIdx.x, lane = tid & 63, wave = tid >> 6;
    int wr = wave >> 1, wc = wave & 1;
    const float* W = (by == 0) ? Wlf : (by == 1) ? Wlb : (by == 2) ? Wrf : Wrb;

    f32x4 acc[4][4] = {};

    for (int k0 = 0; k0 < 256; k0 += 32) {
        #pragma unroll
        for (int c = 0; c < 4; ++c) {
            int t = c * 256 + tid;          // which 16B slot of the 16KB tile
            int row = t >> 3, q = t & 7;    // 8 x 16B per 128B row
            int qs = q ^ (row & 7);         // pre-swizzled source quarter
            int gm = mBase + row; gm = gm < N_NODES ? gm : N_NODES - 1;  // clamp tail
            float* ldsA = &As[(c * 256 + wave * 64) * 4];
            float* ldsB = &Bs[(c * 256 + wave * 64) * 4];
            gload_lds16(x + (size_t)gm * 256 + k0 + qs * 4, ldsA);
            gload_lds16(W + (size_t)row * 256 + k0 + qs * 4, ldsB);
        }
        asm volatile("s_waitcnt vmcnt(0)" ::: "memory");
        __syncthreads();

        bf16x8 af[4], bfr[4];
        int q0 = (lane >> 4) * 2;
        #pragma unroll
        for (int m = 0; m < 4; ++m) {
            int row = wr * 64 + m * 16 + (lane & 15);
            f32x4 p0 = *(const f32x4*)&As[row * 32 + ((q0 ^ (row & 7)) * 4)];
            f32x4 p1 = *(const f32x4*)&As[row * 32 + (((q0 + 1) ^ (row & 7)) * 4)];
            f32x8 w;
            #pragma unroll
            for (int j = 0; j < 4; ++j) { w[j] = p0[j]; w[4 + j] = p1[j]; }
            af[m] = __builtin_convertvector(w, bf16x8);
        }
        #pragma unroll
        for (int n = 0; n < 4; ++n) {
            int row = wc * 64 + n * 16 + (lane & 15);
            f32x4 p0 = *(const f32x4*)&Bs[row * 32 + ((q0 ^ (row & 7)) * 4)];
            f32x4 p1 = *(const f32x4*)&Bs[row * 32 + (((q0 + 1) ^ (row & 7)) * 4)];
            f32x8 w;
            #pragma unroll
            for (int j = 0; j < 4; ++j) { w[j] = p0[j]; w[4 + j] = p1[j]; }
            bfr[n] = __builtin_convertvector(w, bf16x8);
        }
        #pragma unroll
        for (int m = 0; m < 4; ++m)
            #pragma unroll
            for (int n = 0; n < 4; ++n)
                acc[m][n] = __builtin_amdgcn_mfma_f32_16x16x32_bf16(af[m], bfr[n], acc[m][n], 0, 0, 0);
        __syncthreads();
    }

    bool toY = by < 2;
    int cBase = (by & 1) * 128 + wc * 64;   // column within the 256-col half-space
    #pragma unroll
    for (int m = 0; m < 4; ++m) {
        int gm0 = mBase + wr * 64 + m * 16 + (lane >> 4) * 4;
        #pragma unroll
        for (int n = 0; n < 4; ++n) {
            int gn = cBase + n * 16 + (lane & 15);
            f32x4 v = acc[m][n];
            #pragma unroll
            for (int j = 0; j < 4; ++j) {
                int gm = gm0 + j;
                if (gm < N_NODES) {
                    if (toY) Y[(size_t)gm * 256 + gn] = f2bf(v[j]);
                    else     Z[(size_t)gm * 256 + gn] = v[j];
                }
            }
        }
    }
}

// ---------------------------------------------------------------------------
// Aggregation: one wave per (node,dir) stream. Wave loads 64 edge ids
// coalesced, shfl-broadcasts, 4 independent 256B row-gathers in flight
// (ushort2/lane). h = aggr/deg + Z (bias cancels in BatchNorm).
// BN stats: per-lane registers -> LDS pair-reduce -> atomics.
// ---------------------------------------------------------------------------
#define AGG_NODES 8
__global__ __launch_bounds__(256) void aggregate_kernel(
    const unsigned int* __restrict__ Yu,
    const int* __restrict__ offF, const int* __restrict__ listF,
    const int* __restrict__ offB, const int* __restrict__ listB,
    float* __restrict__ H, float* __restrict__ stats)
{
    int tid = threadIdx.x;
    int lane = tid & 63;
    int wave = tid >> 6;
    int dir = wave >> 1;                    // 0 fwd, 1 bwd
    const int* off  = dir ? offB : offF;
    const int* list = dir ? listB : listF;
    int ci = dir * 64 + lane;               // uint col in Yu (128 uints/row)
    int nodeBase = blockIdx.x * AGG_NODES + (wave & 1) * (AGG_NODES / 2);

    float s1a = 0.f, s1b = 0.f, s2a = 0.f, s2b = 0.f;
    for (int jn = 0; jn < AGG_NODES / 2; ++jn) {
        int n = nodeBase + jn;
        if (n < N_NODES) {
            int beg = off[n], end = off[n + 1];
            float a0 = 0.f, a1 = 0.f;
            for (int i = beg; i < end; i += 64) {
                int rem = end - i;
                int cnt = rem < 64 ? rem : 64;
                int u_l = (lane < cnt) ? list[i + lane] : 0;
                int jj = 0;
                for (; jj + 4 <= cnt; jj += 4) {
                    int u0 = __shfl(u_l, jj + 0), u1 = __shfl(u_l, jj + 1);
                    int u2 = __shfl(u_l, jj + 2), u3 = __shfl(u_l, jj + 3);
                    unsigned int y0 = Yu[(size_t)u0 * 128 + ci];
                    unsigned int y1 = Yu[(size_t)u1 * 128 + ci];
                    unsigned int y2 = Yu[(size_t)u2 * 128 + ci];
                    unsigned int y3 = Yu[(size_t)u3 * 128 + ci];
                    a0 += __uint_as_float(y0 << 16) + __uint_as_float(y1 << 16)
                        + __uint_as_float(y2 << 16) + __uint_as_float(y3 << 16);
                    a1 += __uint_as_float(y0 & 0xffff0000u) + __uint_as_float(y1 & 0xffff0000u)
                        + __uint_as_float(y2 & 0xffff0000u) + __uint_as_float(y3 & 0xffff0000u);
                }
                for (; jj < cnt; ++jj) {
                    int u = __shfl(u_l, jj);
                    unsigned int y = Yu[(size_t)u * 128 + ci];
                    a0 += __uint_as_float(y << 16);
                    a1 += __uint_as_float(y & 0xffff0000u);
                }
            }
            float inv = 1.f / fmaxf((float)(end - beg), 1.f);
            float2* hp = (float2*)(H + (size_t)n * 256 + dir * 128) + lane;
            float2 z = *hp;
            float h0 = a0 * inv + z.x;
            float h1 = a1 * inv + z.y;
            *hp = make_float2(h0, h1);
            s1a += h0; s2a += h0 * h0;
            s1b += h1; s2b += h1 * h1;
        }
    }

    __shared__ float red[2][64][4];
    if (wave & 1) {
        red[dir][lane][0] = s1a; red[dir][lane][1] = s1b;
        red[dir][lane][2] = s2a; red[dir][lane][3] = s2b;
    }
    __syncthreads();
    if (!(wave & 1)) {
        s1a += red[dir][lane][0]; s1b += red[dir][lane][1];
        s2a += red[dir][lane][2]; s2b += red[dir][lane][3];
        int c0 = dir * 128 + lane * 2;
        atomicAdd(&stats[c0], s1a);
        atomicAdd(&stats[c0 + 1], s1b);
        atomicAdd(&stats[256 + c0], s2a);
        atomicAdd(&stats[256 + c0 + 1], s2b);
    }
}

// ---------------------------------------------------------------------------
// BatchNorm finalize + ReLU, in place on d_out.
// ---------------------------------------------------------------------------
__global__ __launch_bounds__(256) void bn_kernel(
    const float* __restrict__ stats, const float* __restrict__ gamma,
    const float* __restrict__ beta, float* __restrict__ H)
{
    __shared__ float sc[256], sf[256];
    int tid = threadIdx.x;
    {
        float mean = stats[tid] * (1.f / N_NODES);
        float var  = stats[256 + tid] * (1.f / N_NODES) - mean * mean;
        float s = rsqrtf(fmaxf(var, 0.f) + BN_EPS) * gamma[tid];
        sc[tid] = s;
        sf[tid] = beta[tid] - mean * s;
    }
    __syncthreads();
    for (int n = blockIdx.x; n < N_NODES; n += gridDim.x) {
        size_t idx = (size_t)n * 256 + tid;
        float h = H[idx];
        H[idx] = fmaxf(h * sc[tid] + sf[tid], 0.f);
    }
}

// ---------------------------------------------------------------------------
extern "C" void kernel_launch(void* const* d_in, const int* in_sizes, int n_in,
                              void* d_out, int out_size, void* d_ws, size_t ws_size,
                              hipStream_t stream) {
    const float* x     = (const float*)d_in[0];
    const int*   edge  = (const int*)d_in[1];   // [2][N_EDGES] as int32
    const float* Wlf   = (const float*)d_in[2];
    // d_in[3] = b_l_f : bias cancels under BatchNorm (per-column shift) - unused
    const float* Wrf   = (const float*)d_in[4];
    const float* Wlb   = (const float*)d_in[5];
    // d_in[6] = b_l_b : unused (cancels)
    const float* Wrb   = (const float*)d_in[7];
    const float* gamma = (const float*)d_in[8];
    const float* beta  = (const float*)d_in[9];
    float* out = (float*)d_out;

    const int* src = edge;
    const int* dst = edge + N_EDGES;

    char* ws = (char*)d_ws;
    size_t off = 0;
    auto alloc = [&](size_t bytes) { size_t r = off; off += (bytes + 255) & ~(size_t)255; return r; };
    unsigned short* Y = (unsigned short*)(ws + alloc((size_t)N_NODES * 256 * 2)); // 10.24 MB
    int* offF  = (int*)(ws + alloc((size_t)(N_NODES + 1) * 4));
    int* offB  = (int*)(ws + alloc((size_t)(N_NODES + 1) * 4));
    int* listF = (int*)(ws + alloc((size_t)N_EDGES * 4));
    int* listB = (int*)(ws + alloc((size_t)N_EDGES * 4));
    size_t zbase_off = off;
    int* cntF = (int*)(ws + alloc((size_t)N_NODES * 4));
    int* cntB = (int*)(ws + alloc((size_t)N_NODES * 4));
    int* curF = (int*)(ws + alloc((size_t)N_NODES * 4));
    int* curB = (int*)(ws + alloc((size_t)N_NODES * 4));
    float* stats = (float*)(ws + alloc(512 * 4));
    size_t zbytes = off - zbase_off;

    hipMemsetAsync(ws + zbase_off, 0, zbytes, stream);

    count_kernel<<<(N_EDGES + 255) / 256, 256, 0, stream>>>(src, dst, cntF, cntB);
    scan_kernel<<<2, 1024, 0, stream>>>(cntF, offF, cntB, offB);
    fill_kernel<<<(N_EDGES + 255) / 256, 256, 0, stream>>>(src, dst, offF, offB, curF, curB, listF, listB);

    dim3 ggrid((N_NODES + 127) / 128, 4);
    mfma_gemm_kernel<<<ggrid, 256, 0, stream>>>(x, Wlf, Wlb, Wrf, Wrb, Y, out);

    aggregate_kernel<<<N_NODES / AGG_NODES, 256, 0, stream>>>(
        (const unsigned int*)Y, offF, listF, offB, listB, out, (float*)stats);

    bn_kernel<<<2048, 256, 0, stream>>>(stats, gamma, beta, out);
}

// Round 3
// 159.029 us; speedup vs baseline: 2.2808x; 1.6951x over previous
//
#include <hip/hip_runtime.h>
#include <hip/hip_bf16.h>

#define N_NODES 20000
#define N_EDGES 320000
#define BN_EPS  1e-5f

typedef __attribute__((ext_vector_type(4))) float f32x4;
typedef __attribute__((ext_vector_type(8))) __bf16 bf16x8;
typedef __attribute__((ext_vector_type(4))) unsigned short u16x4;

__device__ __forceinline__ unsigned short f2bf(float f) {   // RNE f32->bf16
    unsigned int u = __float_as_uint(f);
    u += 0x7fffu + ((u >> 16) & 1u);
    return (unsigned short)(u >> 16);
}
__device__ __forceinline__ float bflo(unsigned int u) { return __uint_as_float(u << 16); }
__device__ __forceinline__ float bfhi(unsigned int u) { return __uint_as_float(u & 0xffff0000u); }

__device__ __forceinline__ void gload_lds16(const void* g, void* l) {
    __builtin_amdgcn_global_load_lds(
        (const __attribute__((address_space(1))) void*)g,
        (__attribute__((address_space(3))) void*)l, 16, 0, 0);
}

// ---------------------------------------------------------------------------
// CSR build: count, scan, fill
// ---------------------------------------------------------------------------
__global__ void count_kernel(const int* __restrict__ src, const int* __restrict__ dst,
                             int* __restrict__ cntF, int* __restrict__ cntB) {
    int e = blockIdx.x * blockDim.x + threadIdx.x;
    if (e < N_EDGES) {
        atomicAdd(&cntF[dst[e]], 1);
        atomicAdd(&cntB[src[e]], 1);
    }
}

#define SCAN_PER 20
__global__ __launch_bounds__(1024) void scan_kernel(const int* __restrict__ cntF, int* __restrict__ offF,
                                                    const int* __restrict__ cntB, int* __restrict__ offB) {
    const int* in  = blockIdx.x ? cntB : cntF;
    int*       out = blockIdx.x ? offB : offF;
    int t = threadIdx.x;
    int base = t * SCAN_PER;
    int v[SCAN_PER];
    int sum = 0;
    #pragma unroll
    for (int k = 0; k < SCAN_PER; ++k) {
        int i = base + k;
        int c = (i < N_NODES) ? in[i] : 0;
        v[k] = sum; sum += c;
    }
    __shared__ int sh[1024];
    sh[t] = sum;
    __syncthreads();
    for (int o = 1; o < 1024; o <<= 1) {
        int x = (t >= o) ? sh[t - o] : 0;
        __syncthreads();
        sh[t] += x;
        __syncthreads();
    }
    int pre = t ? sh[t - 1] : 0;
    #pragma unroll
    for (int k = 0; k < SCAN_PER; ++k) {
        int i = base + k;
        if (i < N_NODES) out[i] = pre + v[k];
    }
    if (t == 1023) out[N_NODES] = sh[1023];
}

__global__ void fill_kernel(const int* __restrict__ src, const int* __restrict__ dst,
                            const int* __restrict__ offF, const int* __restrict__ offB,
                            int* __restrict__ curF, int* __restrict__ curB,
                            int* __restrict__ listF, int* __restrict__ listB) {
    int e = blockIdx.x * blockDim.x + threadIdx.x;
    if (e < N_EDGES) {
        int s = src[e], d = dst[e];
        int p = atomicAdd(&curF[d], 1);
        listF[offF[d] + p] = s;
        int q = atomicAdd(&curB[s], 1);
        listB[offB[s] + q] = d;
    }
}

// ---------------------------------------------------------------------------
// Convert x (20000x256) and the four W mats (each 128x256) to bf16.
// Wb layout: [512][256], mat order {W_l_f, W_l_b, W_r_f, W_r_b} (matches by).
// ---------------------------------------------------------------------------
__global__ __launch_bounds__(256) void cvt_kernel(
    const float* __restrict__ x,
    const float* __restrict__ Wlf, const float* __restrict__ Wlb,
    const float* __restrict__ Wrf, const float* __restrict__ Wrb,
    unsigned short* __restrict__ Xb, unsigned short* __restrict__ Wb)
{
    const int XQ = N_NODES * 256 / 4;         // 1,280,000 float4s
    const int WQ = 128 * 256 / 4;             // 8,192 per matrix
    const int total = XQ + 4 * WQ;
    for (int i = blockIdx.x * blockDim.x + threadIdx.x; i < total; i += gridDim.x * blockDim.x) {
        const float* sp;
        unsigned short* dp;
        if (i < XQ) {
            sp = x + (size_t)i * 4;
            dp = Xb + (size_t)i * 4;
        } else {
            int w = i - XQ;
            int mat = w / WQ;
            int o = (w - mat * WQ) * 4;
            if      (mat == 0) sp = Wlf + o;
            else if (mat == 1) sp = Wlb + o;
            else if (mat == 2) sp = Wrf + o;
            else               sp = Wrb + o;
            dp = Wb + (size_t)mat * 32768 + o;
        }
        float4 v = *(const float4*)sp;
        u16x4 r = {f2bf(v.x), f2bf(v.y), f2bf(v.z), f2bf(v.w)};
        *(u16x4*)dp = r;
    }
}

// ---------------------------------------------------------------------------
// bf16 MFMA GEMM: [20000,256] x 512 output cols. BK=64, 32KB LDS, 4 waves,
// 128x128 output per block. XOR-swizzled global_load_lds staging (pre-swizzled
// source slot + swizzled ds_read; rule #21 both-sides involution).
// grid.y: 0 -> Y[:,0:128] (Wlf), 1 -> Y[:,128:256] (Wlb),
//         2 -> H[:,0:128] (Wrf), 3 -> H[:,128:256] (Wrb)
// ---------------------------------------------------------------------------
__global__ __launch_bounds__(256) void mfma_gemm_kernel(
    const unsigned short* __restrict__ Xb, const unsigned short* __restrict__ Wb,
    unsigned short* __restrict__ Y, float* __restrict__ Z)
{
    __shared__ unsigned short As[128 * 64];   // 16 KB
    __shared__ unsigned short Bs[128 * 64];   // 16 KB
    int by = blockIdx.y;
    int mBase = blockIdx.x * 128;
    int tid = threadIdx.x, lane = tid & 63, wave = tid >> 6;
    int wr = wave >> 1, wc = wave & 1;
    const unsigned short* W = Wb + (size_t)by * 128 * 256;

    f32x4 acc[4][4] = {};

    for (int k0 = 0; k0 < 256; k0 += 64) {
        #pragma unroll
        for (int c = 0; c < 4; ++c) {
            int S = c * 256 + tid;                 // 16B slot index, 0..1023
            int row = S >> 3;
            int q = (S & 7) ^ (row & 7);           // pre-swizzled source slot
            int gm = mBase + row; gm = gm < N_NODES ? gm : N_NODES - 1;
            gload_lds16(Xb + (size_t)gm * 256 + k0 + q * 8, &As[S * 8]);
            gload_lds16(W + (size_t)row * 256 + k0 + q * 8, &Bs[S * 8]);
        }
        asm volatile("s_waitcnt vmcnt(0)" ::: "memory");
        __syncthreads();

        #pragma unroll
        for (int ks = 0; ks < 2; ++ks) {
            bf16x8 af[4], bfr[4];
            int sl = ks * 4 + (lane >> 4);
            #pragma unroll
            for (int m = 0; m < 4; ++m) {
                int row = wr * 64 + m * 16 + (lane & 15);
                af[m] = *(const bf16x8*)&As[row * 64 + ((sl ^ (row & 7)) * 8)];
            }
            #pragma unroll
            for (int n = 0; n < 4; ++n) {
                int row = wc * 64 + n * 16 + (lane & 15);
                bfr[n] = *(const bf16x8*)&Bs[row * 64 + ((sl ^ (row & 7)) * 8)];
            }
            #pragma unroll
            for (int m = 0; m < 4; ++m)
                #pragma unroll
                for (int n = 0; n < 4; ++n)
                    acc[m][n] = __builtin_amdgcn_mfma_f32_16x16x32_bf16(af[m], bfr[n], acc[m][n], 0, 0, 0);
        }
        __syncthreads();
    }

    bool toY = by < 2;
    int cBase = (by & 1) * 128 + wc * 64;
    #pragma unroll
    for (int m = 0; m < 4; ++m) {
        int gm0 = mBase + wr * 64 + m * 16 + (lane >> 4) * 4;
        #pragma unroll
        for (int n = 0; n < 4; ++n) {
            int gn = cBase + n * 16 + (lane & 15);
            f32x4 v = acc[m][n];
            #pragma unroll
            for (int j = 0; j < 4; ++j) {
                int gm = gm0 + j;
                if (gm < N_NODES) {
                    if (toY) Y[(size_t)gm * 256 + gn] = f2bf(v[j]);
                    else     Z[(size_t)gm * 256 + gn] = v[j];
                }
            }
        }
    }
}

// ---------------------------------------------------------------------------
// Aggregation: wave = one (node,dir) stream, 2 nodes/wave. 16B gathers:
// 16 lanes cover one row (128 bf16 cols), so one wave-load gathers 4 edges;
// 4 loads (16 edges) in flight. Cross-group shfl_xor reduce, then
// h = aggr/deg + Z (read from H), write back. No LDS, ~full occupancy.
// ---------------------------------------------------------------------------
#define NPW 2
__global__ __launch_bounds__(256) void aggregate_kernel(
    const unsigned short* __restrict__ Y,
    const int* __restrict__ offF, const int* __restrict__ listF,
    const int* __restrict__ offB, const int* __restrict__ listB,
    float* __restrict__ H)
{
    int tid = threadIdx.x, lane = tid & 63, wave = tid >> 6;
    int dir = wave >> 1, half = wave & 1;
    const int* off  = dir ? offB : offF;
    const int* list = dir ? listB : listF;
    int eg = lane >> 4;        // which edge of the group of 4
    int c16 = lane & 15;       // 16B column slot within the row
    int nodeBase = blockIdx.x * (2 * NPW) + half * NPW;

    for (int jn = 0; jn < NPW; ++jn) {
        int n = nodeBase + jn;                 // grid exact: always < N_NODES
        int beg = off[n], end = off[n + 1];
        int deg = end - beg;
        float acc[8] = {0.f, 0.f, 0.f, 0.f, 0.f, 0.f, 0.f, 0.f};

        for (int i = beg; i < end; i += 64) {
            int c = end - i; if (c > 64) c = 64;
            int u_l = list[i + (lane < c ? lane : c - 1)];
            int nb = (c + 15) >> 4;
            for (int b = 0; b < nb; ++b) {
                uint4 v[4]; float mk[4];
                #pragma unroll
                for (int k = 0; k < 4; ++k) {
                    int ei = b * 16 + k * 4 + eg;
                    mk[k] = (ei < c) ? 1.f : 0.f;
                    int u = __shfl(u_l, ei < c ? ei : c - 1);
                    v[k] = *(const uint4*)(Y + (size_t)u * 256 + dir * 128 + c16 * 8);
                }
                #pragma unroll
                for (int k = 0; k < 4; ++k) {
                    acc[0] = fmaf(mk[k], bflo(v[k].x), acc[0]);
                    acc[1] = fmaf(mk[k], bfhi(v[k].x), acc[1]);
                    acc[2] = fmaf(mk[k], bflo(v[k].y), acc[2]);
                    acc[3] = fmaf(mk[k], bfhi(v[k].y), acc[3]);
                    acc[4] = fmaf(mk[k], bflo(v[k].z), acc[4]);
                    acc[5] = fmaf(mk[k], bfhi(v[k].z), acc[5]);
                    acc[6] = fmaf(mk[k], bflo(v[k].w), acc[6]);
                    acc[7] = fmaf(mk[k], bfhi(v[k].w), acc[7]);
                }
            }
        }
        #pragma unroll
        for (int j = 0; j < 8; ++j) {
            acc[j] += __shfl_xor(acc[j], 16);
            acc[j] += __shfl_xor(acc[j], 32);
        }
        // static-index select of this lane's two columns (rule #20: no runtime
        // array index -> cndmask chain, no scratch)
        float h0 = (eg & 2) ? ((eg & 1) ? acc[6] : acc[4]) : ((eg & 1) ? acc[2] : acc[0]);
        float h1 = (eg & 2) ? ((eg & 1) ? acc[7] : acc[5]) : ((eg & 1) ? acc[3] : acc[1]);
        float inv = 1.f / fmaxf((float)deg, 1.f);
        float2* hp = (float2*)(H + (size_t)n * 256 + dir * 128 + c16 * 8 + eg * 2);
        float2 z = *hp;
        *hp = make_float2(fmaf(h0, inv, z.x), fmaf(h1, inv, z.y));
    }
}

// ---------------------------------------------------------------------------
// BN stats: column sums of H (coalesced, 512 contributions per stat address).
// ---------------------------------------------------------------------------
__global__ __launch_bounds__(256) void bn_stats_kernel(const float* __restrict__ H,
                                                       float* __restrict__ stats) {
    int col = threadIdx.x;
    float s1 = 0.f, s2 = 0.f;
    for (int n = blockIdx.x; n < N_NODES; n += gridDim.x) {
        float h = H[(size_t)n * 256 + col];
        s1 += h;
        s2 += h * h;
    }
    atomicAdd(&stats[col], s1);
    atomicAdd(&stats[256 + col], s2);
}

// ---------------------------------------------------------------------------
// BatchNorm finalize + ReLU, in place on d_out.
// ---------------------------------------------------------------------------
__global__ __launch_bounds__(256) void bn_kernel(
    const float* __restrict__ stats, const float* __restrict__ gamma,
    const float* __restrict__ beta, float* __restrict__ H)
{
    __shared__ float sc[256], sf[256];
    int tid = threadIdx.x;
    {
        float mean = stats[tid] * (1.f / N_NODES);
        float var  = stats[256 + tid] * (1.f / N_NODES) - mean * mean;
        float s = rsqrtf(fmaxf(var, 0.f) + BN_EPS) * gamma[tid];
        sc[tid] = s;
        sf[tid] = beta[tid] - mean * s;
    }
    __syncthreads();
    for (int n = blockIdx.x; n < N_NODES; n += gridDim.x) {
        size_t idx = (size_t)n * 256 + tid;
        float h = H[idx];
        H[idx] = fmaxf(h * sc[tid] + sf[tid], 0.f);
    }
}

// ---------------------------------------------------------------------------
extern "C" void kernel_launch(void* const* d_in, const int* in_sizes, int n_in,
                              void* d_out, int out_size, void* d_ws, size_t ws_size,
                              hipStream_t stream) {
    const float* x     = (const float*)d_in[0];
    const int*   edge  = (const int*)d_in[1];   // [2][N_EDGES]
    const float* Wlf   = (const float*)d_in[2];
    // d_in[3] = b_l_f : cancels under BatchNorm (per-column shift) - unused
    const float* Wrf   = (const float*)d_in[4];
    const float* Wlb   = (const float*)d_in[5];
    // d_in[6] = b_l_b : unused (cancels)
    const float* Wrb   = (const float*)d_in[7];
    const float* gamma = (const float*)d_in[8];
    const float* beta  = (const float*)d_in[9];
    float* out = (float*)d_out;

    const int* src = edge;
    const int* dst = edge + N_EDGES;

    char* ws = (char*)d_ws;
    size_t off = 0;
    auto alloc = [&](size_t bytes) { size_t r = off; off += (bytes + 255) & ~(size_t)255; return r; };
    unsigned short* Y  = (unsigned short*)(ws + alloc((size_t)N_NODES * 256 * 2)); // 10.24 MB
    unsigned short* Xb = (unsigned short*)(ws + alloc((size_t)N_NODES * 256 * 2)); // 10.24 MB
    unsigned short* Wb = (unsigned short*)(ws + alloc((size_t)4 * 128 * 256 * 2)); // 256 KB
    int* offF  = (int*)(ws + alloc((size_t)(N_NODES + 1) * 4));
    int* offB  = (int*)(ws + alloc((size_t)(N_NODES + 1) * 4));
    int* listF = (int*)(ws + alloc((size_t)N_EDGES * 4));
    int* listB = (int*)(ws + alloc((size_t)N_EDGES * 4));
    size_t zbase_off = off;
    int* cntF = (int*)(ws + alloc((size_t)N_NODES * 4));
    int* cntB = (int*)(ws + alloc((size_t)N_NODES * 4));
    int* curF = (int*)(ws + alloc((size_t)N_NODES * 4));
    int* curB = (int*)(ws + alloc((size_t)N_NODES * 4));
    float* stats = (float*)(ws + alloc(512 * 4));
    size_t zbytes = off - zbase_off;

    hipMemsetAsync(ws + zbase_off, 0, zbytes, stream);

    cvt_kernel<<<2048, 256, 0, stream>>>(x, Wlf, Wlb, Wrf, Wrb, Xb, Wb);

    count_kernel<<<(N_EDGES + 255) / 256, 256, 0, stream>>>(src, dst, cntF, cntB);
    scan_kernel<<<2, 1024, 0, stream>>>(cntF, offF, cntB, offB);
    fill_kernel<<<(N_EDGES + 255) / 256, 256, 0, stream>>>(src, dst, offF, offB, curF, curB, listF, listB);

    dim3 ggrid((N_NODES + 127) / 128, 4);
    mfma_gemm_kernel<<<ggrid, 256, 0, stream>>>(Xb, Wb, Y, out);

    aggregate_kernel<<<N_NODES / (2 * NPW), 256, 0, stream>>>(
        Y, offF, listF, offB, listB, out);

    bn_stats_kernel<<<512, 256, 0, stream>>>(out, stats);
    bn_kernel<<<2048, 256, 0, stream>>>(stats, gamma, beta, out);
}

// Round 5
// 150.899 us; speedup vs baseline: 2.4036x; 1.0539x over previous
//
#include <hip/hip_runtime.h>
#include <hip/hip_bf16.h>

#define N_NODES 20000
#define N_EDGES 320000
#define BN_EPS  1e-5f

#define FILL_BLK ((N_EDGES + 255) / 256)    // 1250
#define GEMM_MT  ((N_NODES + 127) / 128)    // 157

typedef __attribute__((ext_vector_type(4))) float f32x4;
typedef __attribute__((ext_vector_type(8))) __bf16 bf16x8;
typedef __attribute__((ext_vector_type(4))) unsigned short u16x4;

__device__ __forceinline__ unsigned short f2bf(float f) {   // RNE f32->bf16
    unsigned int u = __float_as_uint(f);
    u += 0x7fffu + ((u >> 16) & 1u);
    return (unsigned short)(u >> 16);
}
__device__ __forceinline__ float bflo(unsigned int u) { return __uint_as_float(u << 16); }
__device__ __forceinline__ float bfhi(unsigned int u) { return __uint_as_float(u & 0xffff0000u); }

__device__ __forceinline__ void gload_lds16(const void* g, void* l) {
    __builtin_amdgcn_global_load_lds(
        (const __attribute__((address_space(1))) void*)g,
        (__attribute__((address_space(3))) void*)l, 16, 0, 0);
}

// ---------------------------------------------------------------------------
// cvt + zero: convert x and the four W mats to bf16, and zero cnt/cur/stats
// (replaces hipMemsetAsync, whose fill dispatch cost ~41 us in the graph).
// ---------------------------------------------------------------------------
__global__ __launch_bounds__(256) void cvt_zero_kernel(
    const float* __restrict__ x,
    const float* __restrict__ Wlf, const float* __restrict__ Wlb,
    const float* __restrict__ Wrf, const float* __restrict__ Wrb,
    unsigned short* __restrict__ Xb, unsigned short* __restrict__ Wb,
    uint4* __restrict__ zp, int zquads)
{
    const int XQ = N_NODES * 256 / 4;         // 1,280,000
    const int WQ = 128 * 256 / 4;             // 8,192 per matrix
    const int total = XQ + 4 * WQ + zquads;
    for (int i = blockIdx.x * blockDim.x + threadIdx.x; i < total; i += gridDim.x * blockDim.x) {
        if (i >= XQ + 4 * WQ) {
            zp[i - XQ - 4 * WQ] = make_uint4(0, 0, 0, 0);
            continue;
        }
        const float* sp;
        unsigned short* dp;
        if (i < XQ) {
            sp = x + (size_t)i * 4;
            dp = Xb + (size_t)i * 4;
        } else {
            int w = i - XQ;
            int mat = w / WQ;
            int o = (w - mat * WQ) * 4;
            if      (mat == 0) sp = Wlf + o;
            else if (mat == 1) sp = Wlb + o;
            else if (mat == 2) sp = Wrf + o;
            else               sp = Wrb + o;
            dp = Wb + (size_t)mat * 32768 + o;
        }
        float4 v = *(const float4*)sp;
        u16x4 r = {f2bf(v.x), f2bf(v.y), f2bf(v.z), f2bf(v.w)};
        *(u16x4*)dp = r;
    }
}

// ---------------------------------------------------------------------------
// CSR build: count, scan
// ---------------------------------------------------------------------------
__global__ void count_kernel(const int* __restrict__ src, const int* __restrict__ dst,
                             int* __restrict__ cntF, int* __restrict__ cntB) {
    int e = blockIdx.x * blockDim.x + threadIdx.x;
    if (e < N_EDGES) {
        atomicAdd(&cntF[dst[e]], 1);
        atomicAdd(&cntB[src[e]], 1);
    }
}

#define SCAN_PER 20
__global__ __launch_bounds__(1024) void scan_kernel(const int* __restrict__ cntF, int* __restrict__ offF,
                                                    const int* __restrict__ cntB, int* __restrict__ offB) {
    const int* in  = blockIdx.x ? cntB : cntF;
    int*       out = blockIdx.x ? offB : offF;
    int t = threadIdx.x;
    int base = t * SCAN_PER;
    int v[SCAN_PER];
    int sum = 0;
    #pragma unroll
    for (int k = 0; k < SCAN_PER; ++k) {
        int i = base + k;
        int c = (i < N_NODES) ? in[i] : 0;
        v[k] = sum; sum += c;
    }
    __shared__ int sh[1024];
    sh[t] = sum;
    __syncthreads();
    for (int o = 1; o < 1024; o <<= 1) {
        int x = (t >= o) ? sh[t - o] : 0;
        __syncthreads();
        sh[t] += x;
        __syncthreads();
    }
    int pre = t ? sh[t - 1] : 0;
    #pragma unroll
    for (int k = 0; k < SCAN_PER; ++k) {
        int i = base + k;
        if (i < N_NODES) out[i] = pre + v[k];
    }
    if (t == 1023) out[N_NODES] = sh[1023];
}

// ---------------------------------------------------------------------------
// Merged fill + MFMA GEMM (disjoint deps: fill<-scan, gemm<-cvt; co-scheduled
// in one dispatch to hide the latency-bound fill under the GEMM and save a
// launch). Blocks [0,FILL_BLK) do CSR fill; the rest do the bf16 GEMM.
// ---------------------------------------------------------------------------
__global__ __launch_bounds__(256) void fill_gemm_kernel(
    const int* __restrict__ src, const int* __restrict__ dst,
    const int* __restrict__ offF, const int* __restrict__ offB,
    int* __restrict__ curF, int* __restrict__ curB,
    int* __restrict__ listF, int* __restrict__ listB,
    const unsigned short* __restrict__ Xb, const unsigned short* __restrict__ Wb,
    unsigned short* __restrict__ Y, float* __restrict__ Z)
{
    __shared__ unsigned short As[128 * 64];   // 16 KB
    __shared__ unsigned short Bs[128 * 64];   // 16 KB

    if (blockIdx.x < FILL_BLK) {
        int e = blockIdx.x * blockDim.x + threadIdx.x;
        if (e < N_EDGES) {
            int s = src[e], d = dst[e];
            int p = atomicAdd(&curF[d], 1);
            listF[offF[d] + p] = s;
            int q = atomicAdd(&curB[s], 1);
            listB[offB[s] + q] = d;
        }
        return;
    }

    int gb = blockIdx.x - FILL_BLK;
    int by = gb & 3;
    int mBase = (gb >> 2) * 128;
    int tid = threadIdx.x, lane = tid & 63, wave = tid >> 6;
    int wr = wave >> 1, wc = wave & 1;
    const unsigned short* W = Wb + (size_t)by * 128 * 256;

    f32x4 acc[4][4] = {};

    for (int k0 = 0; k0 < 256; k0 += 64) {
        #pragma unroll
        for (int c = 0; c < 4; ++c) {
            int S = c * 256 + tid;                 // 16B slot index, 0..1023
            int row = S >> 3;
            int q = (S & 7) ^ (row & 7);           // pre-swizzled source slot
            int gm = mBase + row; gm = gm < N_NODES ? gm : N_NODES - 1;
            gload_lds16(Xb + (size_t)gm * 256 + k0 + q * 8, &As[S * 8]);
            gload_lds16(W + (size_t)row * 256 + k0 + q * 8, &Bs[S * 8]);
        }
        asm volatile("s_waitcnt vmcnt(0)" ::: "memory");
        __syncthreads();

        #pragma unroll
        for (int ks = 0; ks < 2; ++ks) {
            bf16x8 af[4], bfr[4];
            int sl = ks * 4 + (lane >> 4);
            #pragma unroll
            for (int m = 0; m < 4; ++m) {
                int row = wr * 64 + m * 16 + (lane & 15);
                af[m] = *(const bf16x8*)&As[row * 64 + ((sl ^ (row & 7)) * 8)];
            }
            #pragma unroll
            for (int n = 0; n < 4; ++n) {
                int row = wc * 64 + n * 16 + (lane & 15);
                bfr[n] = *(const bf16x8*)&Bs[row * 64 + ((sl ^ (row & 7)) * 8)];
            }
            #pragma unroll
            for (int m = 0; m < 4; ++m)
                #pragma unroll
                for (int n = 0; n < 4; ++n)
                    acc[m][n] = __builtin_amdgcn_mfma_f32_16x16x32_bf16(af[m], bfr[n], acc[m][n], 0, 0, 0);
        }
        __syncthreads();
    }

    bool toY = by < 2;
    int cBase = (by & 1) * 128 + wc * 64;
    #pragma unroll
    for (int m = 0; m < 4; ++m) {
        int gm0 = mBase + wr * 64 + m * 16 + (lane >> 4) * 4;
        #pragma unroll
        for (int n = 0; n < 4; ++n) {
            int gn = cBase + n * 16 + (lane & 15);
            f32x4 v = acc[m][n];
            #pragma unroll
            for (int j = 0; j < 4; ++j) {
                int gm = gm0 + j;
                if (gm < N_NODES) {
                    if (toY) Y[(size_t)gm * 256 + gn] = f2bf(v[j]);
                    else     Z[(size_t)gm * 256 + gn] = v[j];
                }
            }
        }
    }
}

// ---------------------------------------------------------------------------
// Aggregation: wave = one (node,dir) stream, 2 nodes/wave. 16 lanes cover one
// 128-col bf16 row (16B/lane), so one wave-load gathers 4 edges; 4 loads
// (16 edges) in flight. __shfl executes UNCONDITIONALLY (ds_bpermute reads 0
// from exec-inactive source lanes — round-4 bug); only the LOAD is predicated.
// Cross-group shfl_xor reduce, h = aggr/deg + Z.
// ---------------------------------------------------------------------------
#define NPW 2
__global__ __launch_bounds__(256) void aggregate_kernel(
    const unsigned short* __restrict__ Y,
    const int* __restrict__ offF, const int* __restrict__ listF,
    const int* __restrict__ offB, const int* __restrict__ listB,
    float* __restrict__ H)
{
    int tid = threadIdx.x, lane = tid & 63, wave = tid >> 6;
    int dir = wave >> 1, half = wave & 1;
    const int* off  = dir ? offB : offF;
    const int* list = dir ? listB : listF;
    int eg = lane >> 4;        // which edge of the group of 4
    int c16 = lane & 15;       // 16B column slot within the row
    int nodeBase = blockIdx.x * (2 * NPW) + half * NPW;

    for (int jn = 0; jn < NPW; ++jn) {
        int n = nodeBase + jn;                 // grid exact: always < N_NODES
        int beg = off[n], end = off[n + 1];
        int deg = end - beg;
        float acc[8] = {0.f, 0.f, 0.f, 0.f, 0.f, 0.f, 0.f, 0.f};

        for (int i = beg; i < end; i += 64) {
            int c = end - i; if (c > 64) c = 64;
            int u_l = list[i + (lane < c ? lane : 0)];
            for (int e0 = 0; e0 < c; e0 += 16) {
                uint4 v[4];
                #pragma unroll
                for (int k = 0; k < 4; ++k) {
                    int ei = e0 + k * 4 + eg;
                    // shfl with ALL lanes active (clamped index), then
                    // predicate only the memory access:
                    int u = __shfl(u_l, ei < c ? ei : 0);
                    v[k] = make_uint4(0u, 0u, 0u, 0u);
                    if (ei < c)
                        v[k] = *(const uint4*)(Y + (size_t)u * 256 + dir * 128 + c16 * 8);
                }
                #pragma unroll
                for (int k = 0; k < 4; ++k) {
                    acc[0] += bflo(v[k].x); acc[1] += bfhi(v[k].x);
                    acc[2] += bflo(v[k].y); acc[3] += bfhi(v[k].y);
                    acc[4] += bflo(v[k].z); acc[5] += bfhi(v[k].z);
                    acc[6] += bflo(v[k].w); acc[7] += bfhi(v[k].w);
                }
            }
        }
        #pragma unroll
        for (int j = 0; j < 8; ++j) {
            acc[j] += __shfl_xor(acc[j], 16);
            acc[j] += __shfl_xor(acc[j], 32);
        }
        // static-index select of this lane's two columns (rule #20)
        float h0 = (eg & 2) ? ((eg & 1) ? acc[6] : acc[4]) : ((eg & 1) ? acc[2] : acc[0]);
        float h1 = (eg & 2) ? ((eg & 1) ? acc[7] : acc[5]) : ((eg & 1) ? acc[3] : acc[1]);
        float inv = 1.f / fmaxf((float)deg, 1.f);
        float2* hp = (float2*)(H + (size_t)n * 256 + dir * 128 + c16 * 8 + eg * 2);
        float2 z = *hp;
        *hp = make_float2(fmaf(h0, inv, z.x), fmaf(h1, inv, z.y));
    }
}

// ---------------------------------------------------------------------------
// BN stats: column sums of H (coalesced, 512 atomics per block).
// ---------------------------------------------------------------------------
__global__ __launch_bounds__(256) void bn_stats_kernel(const float* __restrict__ H,
                                                       float* __restrict__ stats) {
    int col = threadIdx.x;
    float s1 = 0.f, s2 = 0.f;
    for (int n = blockIdx.x; n < N_NODES; n += gridDim.x) {
        float h = H[(size_t)n * 256 + col];
        s1 += h;
        s2 += h * h;
    }
    atomicAdd(&stats[col], s1);
    atomicAdd(&stats[256 + col], s2);
}

// ---------------------------------------------------------------------------
// BatchNorm finalize + ReLU, in place on d_out.
// ---------------------------------------------------------------------------
__global__ __launch_bounds__(256) void bn_kernel(
    const float* __restrict__ stats, const float* __restrict__ gamma,
    const float* __restrict__ beta, float* __restrict__ H)
{
    __shared__ float sc[256], sf[256];
    int tid = threadIdx.x;
    {
        float mean = stats[tid] * (1.f / N_NODES);
        float var  = stats[256 + tid] * (1.f / N_NODES) - mean * mean;
        float s = rsqrtf(fmaxf(var, 0.f) + BN_EPS) * gamma[tid];
        sc[tid] = s;
        sf[tid] = beta[tid] - mean * s;
    }
    __syncthreads();
    for (int n = blockIdx.x; n < N_NODES; n += gridDim.x) {
        size_t idx = (size_t)n * 256 + tid;
        float h = H[idx];
        H[idx] = fmaxf(h * sc[tid] + sf[tid], 0.f);
    }
}

// ---------------------------------------------------------------------------
extern "C" void kernel_launch(void* const* d_in, const int* in_sizes, int n_in,
                              void* d_out, int out_size, void* d_ws, size_t ws_size,
                              hipStream_t stream) {
    const float* x     = (const float*)d_in[0];
    const int*   edge  = (const int*)d_in[1];   // [2][N_EDGES]
    const float* Wlf   = (const float*)d_in[2];
    // d_in[3] = b_l_f : cancels under BatchNorm (per-column shift) - unused
    const float* Wrf   = (const float*)d_in[4];
    const float* Wlb   = (const float*)d_in[5];
    // d_in[6] = b_l_b : unused (cancels)
    const float* Wrb   = (const float*)d_in[7];
    const float* gamma = (const float*)d_in[8];
    const float* beta  = (const float*)d_in[9];
    float* out = (float*)d_out;

    const int* src = edge;
    const int* dst = edge + N_EDGES;

    char* ws = (char*)d_ws;
    size_t off = 0;
    auto alloc = [&](size_t bytes) { size_t r = off; off += (bytes + 255) & ~(size_t)255; return r; };
    unsigned short* Y  = (unsigned short*)(ws + alloc((size_t)N_NODES * 256 * 2)); // 10.24 MB
    unsigned short* Xb = (unsigned short*)(ws + alloc((size_t)N_NODES * 256 * 2)); // 10.24 MB
    unsigned short* Wb = (unsigned short*)(ws + alloc((size_t)4 * 128 * 256 * 2)); // 256 KB
    int* offF  = (int*)(ws + alloc((size_t)(N_NODES + 1) * 4));
    int* offB  = (int*)(ws + alloc((size_t)(N_NODES + 1) * 4));
    int* listF = (int*)(ws + alloc((size_t)N_EDGES * 4));
    int* listB = (int*)(ws + alloc((size_t)N_EDGES * 4));
    size_t zbase_off = off;
    int* cntF = (int*)(ws + alloc((size_t)N_NODES * 4));
    int* cntB = (int*)(ws + alloc((size_t)N_NODES * 4));
    int* curF = (int*)(ws + alloc((size_t)N_NODES * 4));
    int* curB = (int*)(ws + alloc((size_t)N_NODES * 4));
    float* stats = (float*)(ws + alloc(512 * 4));
    size_t zbytes = off - zbase_off;          // 256B-aligned => multiple of 16

    cvt_zero_kernel<<<2048, 256, 0, stream>>>(x, Wlf, Wlb, Wrf, Wrb, Xb, Wb,
                                              (uint4*)(ws + zbase_off), (int)(zbytes / 16));

    count_kernel<<<FILL_BLK, 256, 0, stream>>>(src, dst, cntF, cntB);
    scan_kernel<<<2, 1024, 0, stream>>>(cntF, offF, cntB, offB);

    fill_gemm_kernel<<<FILL_BLK + GEMM_MT * 4, 256, 0, stream>>>(
        src, dst, offF, offB, curF, curB, listF, listB, Xb, Wb, Y, out);

    aggregate_kernel<<<N_NODES / (2 * NPW), 256, 0, stream>>>(
        Y, offF, listF, offB, listB, out);

    bn_stats_kernel<<<512, 256, 0, stream>>>(out, stats);
    bn_kernel<<<2048, 256, 0, stream>>>(stats, gamma, beta, out);
}